// Round 4
// baseline (169.469 us; speedup 1.0000x reference)
//
#include <hip/hip_runtime.h>
#include <hip/hip_cooperative_groups.h>

namespace cg = cooperative_groups;

// Problem: B=16, S=2048, D=64, fp32.
// out[b] = V[b] @ (K[b]^T @ Q[b])   -- avoids the SxS intermediate.
//
// R4: single cooperative kernel (1 graph node instead of 3).
//   Phase 1: P[b][chunk] = K_chunk^T @ Q_chunk  (plain stores, no atomics,
//            no ws zeroing needed)
//   grid.sync()
//   Phase 2: M = sum_c P[b][c] (LDS); O_rows = V_rows @ M
// 256 blocks x 512 threads -> 1 block/CU, co-resident (cooperative-safe).

typedef float vf4 __attribute__((ext_vector_type(4)));
typedef float vf2 __attribute__((ext_vector_type(2)));

#define BATCH 16
#define SEQ   2048
#define DIM   64
#define SCHUNK 128                 // seq rows per block, phase 1
#define NCHUNK (SEQ / SCHUNK)      // 16
#define NBLOCKS (BATCH * NCHUNK)   // 256
#define ROWS2 128                  // V rows per block, phase 2
#define TPADR 132                  // transposed-V row stride (floats), 16B-aligned

__global__ __launch_bounds__(512, 2) void fused_attn_kernel(
        const float* __restrict__ Q, const float* __restrict__ K,
        const float* __restrict__ V, float* __restrict__ O,
        float* __restrict__ P) {
    __shared__ float smem[16384];   // 64 KB, reused across phases
    const int bx = blockIdx.x;
    const int t  = threadIdx.x;
    const int b  = bx >> 4;         // batch
    const int cx = bx & 15;         // chunk (phase 1) / row-block (phase 2)
    const int tx = t & 15;
    const int ty = t >> 4;          // 0..31

    // ================= Phase 1: P[bx] = K_chunk^T @ Q_chunk =================
    {
        float* Ks = smem;                   // [SCHUNK][DIM] = 8192 floats
        float* Qs = smem + SCHUNK * DIM;    // [SCHUNK][DIM]
        const float* Kb = K + ((size_t)b * SEQ + (size_t)cx * SCHUNK) * DIM;
        const float* Qb = Q + ((size_t)b * SEQ + (size_t)cx * SCHUNK) * DIM;

        // 2048 vf4 each; 512 threads -> 4 each, coalesced.
#pragma unroll
        for (int i = 0; i < 4; ++i) {
            int idx = i * 512 + t;
            ((vf4*)Ks)[idx] = __builtin_nontemporal_load(&((const vf4*)Kb)[idx]);
            ((vf4*)Qs)[idx] = __builtin_nontemporal_load(&((const vf4*)Qb)[idx]);
        }
        __syncthreads();

        float acc[2][4] = {};
        for (int s = 0; s < SCHUNK; ++s) {
            vf2 ak = *(const vf2*)&Ks[s * DIM + ty * 2];   // rows ty*2..+1
            vf4 bq = *(const vf4*)&Qs[s * DIM + tx * 4];   // cols tx*4..+3
#pragma unroll
            for (int i = 0; i < 2; ++i)
#pragma unroll
                for (int j = 0; j < 4; ++j) acc[i][j] += ak[i] * bq[j];
        }

        float* Pb = P + (size_t)bx * DIM * DIM;   // P[b][chunk] slab
        vf4 r0 = {acc[0][0], acc[0][1], acc[0][2], acc[0][3]};
        vf4 r1 = {acc[1][0], acc[1][1], acc[1][2], acc[1][3]};
        *(vf4*)&Pb[(ty * 2 + 0) * DIM + tx * 4] = r0;
        *(vf4*)&Pb[(ty * 2 + 1) * DIM + tx * 4] = r1;
    }

    __threadfence();            // device-scope release of the P stores
    cg::this_grid().sync();     // all partials visible; smem reusable

    // ================= Phase 2: O rows = V rows @ sum_c P[b][c] =============
    {
        float* Ml  = smem;               // [DIM][DIM] = 4096 floats
        float* VsT = smem + DIM * DIM;   // [DIM][TPADR] = 8448 floats (50KB tot)
        const float* Pb = P + (size_t)(b * NCHUNK) * DIM * DIM;

        // Reduce 16 partials: 1024 vf4 / 512 threads -> 2 each, coalesced.
#pragma unroll
        for (int i = 0; i < 2; ++i) {
            int idx = i * 512 + t;
            vf4 sum = ((const vf4*)Pb)[idx];
#pragma unroll
            for (int c = 1; c < NCHUNK; ++c)
                sum += ((const vf4*)(Pb + (size_t)c * DIM * DIM))[idx];
            ((vf4*)Ml)[idx] = sum;
        }

        // Stage 128 V rows transposed: VsT[col][row]. 2048 vf4 -> 4 each.
        const float* Vb = V + ((size_t)b * SEQ + (size_t)cx * ROWS2) * DIM;
#pragma unroll
        for (int i = 0; i < 4; ++i) {
            int idx = i * 512 + t;
            int row = idx >> 4;          // 0..127
            int col = (idx & 15) * 4;    // 0..60
            vf4 v = __builtin_nontemporal_load(&((const vf4*)Vb)[idx]);
            VsT[(col + 0) * TPADR + row] = v[0];
            VsT[(col + 1) * TPADR + row] = v[1];
            VsT[(col + 2) * TPADR + row] = v[2];
            VsT[(col + 3) * TPADR + row] = v[3];
        }
        __syncthreads();

        // 4x4 register tile: rows ty*4..+3 (of 128), cols tx*4..+3.
        float acc[4][4] = {};
        for (int dp = 0; dp < DIM; ++dp) {
            vf4 mv = *(const vf4*)&Ml[dp * DIM + tx * 4];
            vf4 av = *(const vf4*)&VsT[dp * TPADR + ty * 4];
#pragma unroll
            for (int i = 0; i < 4; ++i)
#pragma unroll
                for (int j = 0; j < 4; ++j) acc[i][j] += av[i] * mv[j];
        }

        float* Ob = O + ((size_t)b * SEQ + (size_t)cx * ROWS2) * DIM;
#pragma unroll
        for (int i = 0; i < 4; ++i) {
            vf4 o = {acc[i][0], acc[i][1], acc[i][2], acc[i][3]};
            __builtin_nontemporal_store(o, (vf4*)&Ob[(ty * 4 + i) * DIM + tx * 4]);
        }
    }
}

extern "C" void kernel_launch(void* const* d_in, const int* in_sizes, int n_in,
                              void* d_out, int out_size, void* d_ws, size_t ws_size,
                              hipStream_t stream) {
    const float* Q = (const float*)d_in[0];
    const float* K = (const float*)d_in[1];
    const float* V = (const float*)d_in[2];
    float* O = (float*)d_out;
    float* P = (float*)d_ws;   // NBLOCKS * 64*64 floats = 4 MB of partials

    void* args[] = {(void*)&Q, (void*)&K, (void*)&V, (void*)&O, (void*)&P};
    (void)hipLaunchCooperativeKernel((void*)fused_attn_kernel,
                                     dim3(NBLOCKS), dim3(512), args, 0, stream);
}

// Round 5
// 85.434 us; speedup vs baseline: 1.9836x; 1.9836x over previous
//
#include <hip/hip_runtime.h>

// Problem: B=16, S=2048, D=64, fp32.
// out[b] = V[b] @ (K[b]^T @ Q[b])   -- avoids the SxS intermediate.
//
// R5: revert cooperative fusion (grid.sync cost ~65us on 8 XCDs).
// Two plain dispatches, no atomics, no memset:
//   A: P[b][chunk] = K_chunk^T @ Q_chunk   (plain vf4 stores to ws)
//   B: M = sum_c P[b][c] (in-block), O_rows = V_rows @ M
// NT loads dropped: harness restores d_in right before each iter -> L2-warm.

typedef float vf4 __attribute__((ext_vector_type(4)));

#define BATCH 16
#define SEQ   2048
#define DIM   64
#define SCHUNK 128                 // seq rows per block, kernel A
#define NCHUNK (SEQ / SCHUNK)      // 16
#define ROWS2  128                 // V rows per block, kernel B
#define TPADR  132                 // transposed-V row stride (floats), 16B-aligned

// ---------------- Kernel A: P[bx] = K_chunk^T @ Q_chunk ----------------------
// 256 threads, 4x4 register tile: thread (ty,tx) owns M[ty*4..+3][tx*4..+3].
// 64 KB LDS -> 2 blocks/CU -> 8 waves/CU.
__global__ __launch_bounds__(256, 2) void ktq_part_kernel(
        const float* __restrict__ K, const float* __restrict__ Q,
        float* __restrict__ P) {
    __shared__ float Ks[SCHUNK * DIM];   // 32 KB
    __shared__ float Qs[SCHUNK * DIM];   // 32 KB
    const int b     = blockIdx.y;
    const int chunk = blockIdx.x;
    const int t     = threadIdx.x;

    const float* Kb = K + ((size_t)b * SEQ + (size_t)chunk * SCHUNK) * DIM;
    const float* Qb = Q + ((size_t)b * SEQ + (size_t)chunk * SCHUNK) * DIM;

    // Stage: 2048 vf4 each; 256 threads -> 8 each, coalesced.
#pragma unroll
    for (int i = 0; i < 8; ++i) {
        int idx = i * 256 + t;
        ((vf4*)Ks)[idx] = ((const vf4*)Kb)[idx];
        ((vf4*)Qs)[idx] = ((const vf4*)Qb)[idx];
    }
    __syncthreads();

    const int tx = t & 15;   // -> d  (Q) cols  tx*4 .. +3
    const int ty = t >> 4;   // -> d' (K) rows  ty*4 .. +3
    float acc[4][4] = {};

    for (int s = 0; s < SCHUNK; ++s) {
        vf4 ak = *(const vf4*)&Ks[s * DIM + ty * 4];  // 4 distinct/wave, broadcast
        vf4 bq = *(const vf4*)&Qs[s * DIM + tx * 4];  // 16 distinct, 4-fold broadcast
#pragma unroll
        for (int i = 0; i < 4; ++i)
#pragma unroll
            for (int j = 0; j < 4; ++j) acc[i][j] += ak[i] * bq[j];
    }

    float* Pb = P + ((size_t)b * NCHUNK + chunk) * DIM * DIM;
#pragma unroll
    for (int i = 0; i < 4; ++i) {
        vf4 r = {acc[i][0], acc[i][1], acc[i][2], acc[i][3]};
        *(vf4*)&Pb[(ty * 4 + i) * DIM + tx * 4] = r;
    }
}

// ---------------- Kernel B: O rows = V rows @ sum_c P[b][c] ------------------
// 512 threads, 128 rows/block, 4x4 register tile.
__global__ __launch_bounds__(512) void vm_red_kernel(
        const float* __restrict__ V, const float* __restrict__ P,
        float* __restrict__ O) {
    __shared__ float Ml[DIM * DIM];       // 16 KB, M[d'][d]
    __shared__ float VsT[DIM * TPADR];    // 33 KB, transposed: VsT[col][row]
    const int b  = blockIdx.y;
    const int rb = blockIdx.x;
    const int t  = threadIdx.x;

    // Reduce the 16 partials of this batch: 1024 vf4 / 512 thr -> 2 each.
    const float* Pb = P + (size_t)b * NCHUNK * DIM * DIM;
#pragma unroll
    for (int i = 0; i < 2; ++i) {
        int idx = i * 512 + t;
        vf4 sum = ((const vf4*)Pb)[idx];
#pragma unroll
        for (int c = 1; c < NCHUNK; ++c)
            sum += ((const vf4*)(Pb + (size_t)c * DIM * DIM))[idx];
        ((vf4*)Ml)[idx] = sum;
    }

    // Stage 128 V rows transposed: 2048 vf4 -> 4 each (one-time scatter).
    const float* Vb = V + ((size_t)b * SEQ + (size_t)rb * ROWS2) * DIM;
#pragma unroll
    for (int i = 0; i < 4; ++i) {
        int idx = i * 512 + t;
        int row = idx >> 4;          // 0..127
        int col = (idx & 15) * 4;    // 0..60
        vf4 v = ((const vf4*)Vb)[idx];
        VsT[(col + 0) * TPADR + row] = v[0];
        VsT[(col + 1) * TPADR + row] = v[1];
        VsT[(col + 2) * TPADR + row] = v[2];
        VsT[(col + 3) * TPADR + row] = v[3];
    }
    __syncthreads();

    const int tx = t & 15;   // output cols d  = tx*4 .. +3
    const int ty = t >> 4;   // output rows v  = ty*4 .. +3  (0..31 -> 128 rows)
    float acc[4][4] = {};

    for (int dp = 0; dp < DIM; ++dp) {
        vf4 mv = *(const vf4*)&Ml[dp * DIM + tx * 4];
        vf4 av = *(const vf4*)&VsT[dp * TPADR + ty * 4];
#pragma unroll
        for (int i = 0; i < 4; ++i)
#pragma unroll
            for (int j = 0; j < 4; ++j) acc[i][j] += av[i] * mv[j];
    }

    float* Ob = O + ((size_t)b * SEQ + (size_t)rb * ROWS2) * DIM;
#pragma unroll
    for (int i = 0; i < 4; ++i) {
        vf4 o = {acc[i][0], acc[i][1], acc[i][2], acc[i][3]};
        __builtin_nontemporal_store(o, (vf4*)&Ob[(ty * 4 + i) * DIM + tx * 4]);
    }
}

extern "C" void kernel_launch(void* const* d_in, const int* in_sizes, int n_in,
                              void* d_out, int out_size, void* d_ws, size_t ws_size,
                              hipStream_t stream) {
    const float* Q = (const float*)d_in[0];
    const float* K = (const float*)d_in[1];
    const float* V = (const float*)d_in[2];
    float* O = (float*)d_out;
    float* P = (float*)d_ws;   // BATCH*NCHUNK*64*64 floats = 4 MB of partials

    dim3 gridA(NCHUNK, BATCH);        // 256 blocks, 256 thr, 2 blocks/CU
    ktq_part_kernel<<<gridA, 256, 0, stream>>>(K, Q, P);

    dim3 gridB(SEQ / ROWS2, BATCH);   // 256 blocks, 512 thr
    vm_red_kernel<<<gridB, 512, 0, stream>>>(V, P, O);
}